// Round 1
// baseline (1205.086 us; speedup 1.0000x reference)
//
#include <hip/hip_runtime.h>
#include <cstddef>

#define Bdim  16
#define Cdim  256
#define HWdim 1024
#define Mtok  16384   // B*H*W tokens
#define Ncode 8192
#define Kdim  256

// argmin GEMM tiling
#define TM 128
#define TN 128
#define TK 32
#define NSPLIT 4
#define NPER (Ncode / NSPLIT)   // 2048 codes per grid-y split

// ---------------------------------------------------------------------------
// Kernel 1: z [B,C,H,W] -> z_out [B, H*W, C]  (32x32 LDS tile transpose)
__global__ __launch_bounds__(256) void k_transpose(const float* __restrict__ z,
                                                   float* __restrict__ z_out) {
    __shared__ float tile[32][33];
    const int b  = blockIdx.z;
    const int c0 = blockIdx.y * 32;
    const int p0 = blockIdx.x * 32;
    const int tx = threadIdx.x;   // 0..31
    const int ty = threadIdx.y;   // 0..7
    const float* src = z + ((size_t)b * Cdim + c0) * HWdim + p0;
#pragma unroll
    for (int i = 0; i < 32; i += 8)
        tile[ty + i][tx] = src[(size_t)(ty + i) * HWdim + tx];
    __syncthreads();
    float* dst = z_out + ((size_t)b * HWdim + p0) * Cdim + c0;
#pragma unroll
    for (int i = 0; i < 32; i += 8)
        dst[(size_t)(ty + i) * Cdim + tx] = tile[tx][ty + i];
}

// ---------------------------------------------------------------------------
// Kernel 2: wnorm[n] = sum_k w[n][k]^2   (one wave per row)
__global__ __launch_bounds__(64) void k_wnorm(const float* __restrict__ w,
                                              float* __restrict__ wnorm) {
    const int row  = blockIdx.x;
    const int lane = threadIdx.x;
    float4 v = ((const float4*)(w + (size_t)row * Kdim))[lane];
    float s = v.x * v.x + v.y * v.y + v.z * v.z + v.w * v.w;
#pragma unroll
    for (int off = 32; off > 0; off >>= 1)
        s += __shfl_down(s, off, 64);
    if (lane == 0) wnorm[row] = s;
}

// ---------------------------------------------------------------------------
// Kernel 3: tiled fp32 GEMM-argmin.
// score(m,n) = wnorm[n] - 2 * dot(z[m], w[n])   (||z||^2 dropped: row-const)
// Z is pre-scaled by -2 on the way into LDS; acc initialized with wnorm.
// Lexicographic (val, idx) min == "first occurrence of minimum" exactly.
__global__ __launch_bounds__(256, 2) void k_argmin(
        const float* __restrict__ zt, const float* __restrict__ w,
        const float* __restrict__ wnorm,
        float* __restrict__ pval, int* __restrict__ pidx) {
    __shared__ float Zs[TM][TK + 1];   // [m][k], pad +1: za broadcast, wb 4-way
    __shared__ float Ws[TN][TK + 1];
    const int tid = threadIdx.x;       // 0..255
    const int cg  = tid & 15;          // column group: 8 codes
    const int rg  = tid >> 4;          // row group:    8 tokens
    const int m0  = blockIdx.x * TM;
    const int n0  = blockIdx.y * NPER;

    float minv[8];
    int   mini[8];
#pragma unroll
    for (int i = 0; i < 8; ++i) { minv[i] = 3.0e38f; mini[i] = 0x7fffffff; }

    for (int nt = 0; nt < NPER; nt += TN) {
        float acc[8][8];
#pragma unroll
        for (int j = 0; j < 8; ++j) {
            const float wn = wnorm[n0 + nt + cg * 8 + j];
#pragma unroll
            for (int i = 0; i < 8; ++i) acc[i][j] = wn;
        }
        for (int k0 = 0; k0 < Kdim; k0 += TK) {
            __syncthreads();
#pragma unroll
            for (int p = 0; p < 4; ++p) {
                const int q = p * 256 + tid;
                const int r = q >> 3;      // row within tile
                const int f = q & 7;       // float4 slot within k-chunk
                float4 v = *(const float4*)(zt + (size_t)(m0 + r) * Kdim + k0 + f * 4);
                Zs[r][f * 4 + 0] = -2.0f * v.x;
                Zs[r][f * 4 + 1] = -2.0f * v.y;
                Zs[r][f * 4 + 2] = -2.0f * v.z;
                Zs[r][f * 4 + 3] = -2.0f * v.w;
                float4 u = *(const float4*)(w + (size_t)(n0 + nt + r) * Kdim + k0 + f * 4);
                Ws[r][f * 4 + 0] = u.x;
                Ws[r][f * 4 + 1] = u.y;
                Ws[r][f * 4 + 2] = u.z;
                Ws[r][f * 4 + 3] = u.w;
            }
            __syncthreads();
#pragma unroll 4
            for (int k = 0; k < TK; ++k) {
                float za[8], wb[8];
#pragma unroll
                for (int i = 0; i < 8; ++i) za[i] = Zs[rg * 8 + i][k];
#pragma unroll
                for (int j = 0; j < 8; ++j) wb[j] = Ws[cg * 8 + j][k];
#pragma unroll
                for (int i = 0; i < 8; ++i)
#pragma unroll
                    for (int j = 0; j < 8; ++j)
                        acc[i][j] = fmaf(za[i], wb[j], acc[i][j]);
            }
        }
#pragma unroll
        for (int i = 0; i < 8; ++i)
#pragma unroll
            for (int j = 0; j < 8; ++j) {
                const float v  = acc[i][j];
                const int  idx = n0 + nt + cg * 8 + j;
                if (v < minv[i] || (v == minv[i] && idx < mini[i])) {
                    minv[i] = v; mini[i] = idx;
                }
            }
    }

    // block reduction: 16 cg-threads per token row -> one (val,idx) per row
    __syncthreads();
    float* redv = (float*)&Zs[0][0];   // [TM][16] floats (8 KB, fits in Zs)
    int*   redi = (int*)&Ws[0][0];     // [TM][16] ints
#pragma unroll
    for (int i = 0; i < 8; ++i) {
        redv[(rg * 8 + i) * 16 + cg] = minv[i];
        redi[(rg * 8 + i) * 16 + cg] = mini[i];
    }
    __syncthreads();
    if (tid < TM) {
        float bv = 3.0e38f; int bi = 0x7fffffff;
#pragma unroll
        for (int c = 0; c < 16; ++c) {
            const float v = redv[tid * 16 + c];
            const int   x = redi[tid * 16 + c];
            if (v < bv || (v == bv && x < bi)) { bv = v; bi = x; }
        }
        pval[(size_t)blockIdx.y * Mtok + m0 + tid] = bv;
        pidx[(size_t)blockIdx.y * Mtok + m0 + tid] = bi;
    }
}

// ---------------------------------------------------------------------------
// Kernel 4: merge NSPLIT partials, gather z_q = weight[idx], write float idx.
// One wave per token.
__global__ __launch_bounds__(256) void k_gather(
        const float* __restrict__ w,
        const float* __restrict__ pval, const int* __restrict__ pidx,
        float* __restrict__ zq, float* __restrict__ idx_out) {
    const int token = blockIdx.x * 4 + (threadIdx.x >> 6);
    const int lane  = threadIdx.x & 63;
    float bv = 3.0e38f; int bi = 0x7fffffff;
#pragma unroll
    for (int s = 0; s < NSPLIT; ++s) {
        const float v = pval[(size_t)s * Mtok + token];
        const int   x = pidx[(size_t)s * Mtok + token];
        if (v < bv || (v == bv && x < bi)) { bv = v; bi = x; }
    }
    const float4 u = *(const float4*)(w + (size_t)bi * Kdim + lane * 4);
    *(float4*)(zq + (size_t)token * Kdim + lane * 4) = u;
    if (lane == 0) idx_out[token] = (float)bi;
}

// ---------------------------------------------------------------------------
extern "C" void kernel_launch(void* const* d_in, const int* in_sizes, int n_in,
                              void* d_out, int out_size, void* d_ws, size_t ws_size,
                              hipStream_t stream) {
    const float* z = (const float*)d_in[0];
    const float* w = (const float*)d_in[1];

    float* z_out  = (float*)d_out;                          // [16384, 256]
    float* zq     = z_out + (size_t)Mtok * Kdim;            // [16384, 256]
    float* idxout = zq + (size_t)Mtok * Kdim;               // [16384]

    float* wnorm  = (float*)d_ws;                           // [8192]
    float* pval   = wnorm + Ncode;                          // [NSPLIT*16384]
    int*   pidx   = (int*)(pval + (size_t)NSPLIT * Mtok);   // [NSPLIT*16384]

    k_transpose<<<dim3(HWdim / 32, Cdim / 32, Bdim), dim3(32, 8), 0, stream>>>(z, z_out);
    k_wnorm<<<dim3(Ncode), dim3(64), 0, stream>>>(w, wnorm);
    k_argmin<<<dim3(Mtok / TM, NSPLIT), dim3(256), 0, stream>>>(z_out, w, wnorm, pval, pidx);
    k_gather<<<dim3(Mtok / 4), dim3(256), 0, stream>>>(w, pval, pidx, zq, idxout);
}

// Round 2
// 912.719 us; speedup vs baseline: 1.3203x; 1.3203x over previous
//
#include <hip/hip_runtime.h>
#include <cstddef>

#define Bdim  16
#define Cdim  256
#define HWdim 1024
#define Mtok  16384   // B*H*W tokens
#define Ncode 8192
#define Kdim  256

// argmin GEMM tiling
#define TM 128
#define TN 128
#define TK 32
#define LDA 132       // LDS row stride (floats): 128 + 4, keeps 16B alignment
#define NSPLIT 8
#define NPER (Ncode / NSPLIT)   // 1024 codes per grid-y split

// ---------------------------------------------------------------------------
// Kernel 1: z [B,C,H,W] -> z_out [B, H*W, C]  (32x32 LDS tile transpose)
__global__ __launch_bounds__(256) void k_transpose(const float* __restrict__ z,
                                                   float* __restrict__ z_out) {
    __shared__ float tile[32][33];
    const int b  = blockIdx.z;
    const int c0 = blockIdx.y * 32;
    const int p0 = blockIdx.x * 32;
    const int tx = threadIdx.x;   // 0..31
    const int ty = threadIdx.y;   // 0..7
    const float* src = z + ((size_t)b * Cdim + c0) * HWdim + p0;
#pragma unroll
    for (int i = 0; i < 32; i += 8)
        tile[ty + i][tx] = src[(size_t)(ty + i) * HWdim + tx];
    __syncthreads();
    float* dst = z_out + ((size_t)b * HWdim + p0) * Cdim + c0;
#pragma unroll
    for (int i = 0; i < 32; i += 8)
        dst[(size_t)(ty + i) * Cdim + tx] = tile[tx][ty + i];
}

// ---------------------------------------------------------------------------
// Kernel 2: wnorm[n] = sum_k w[n][k]^2   (one wave per row)
__global__ __launch_bounds__(64) void k_wnorm(const float* __restrict__ w,
                                              float* __restrict__ wnorm) {
    const int row  = blockIdx.x;
    const int lane = threadIdx.x;
    float4 v = ((const float4*)(w + (size_t)row * Kdim))[lane];
    float s = v.x * v.x + v.y * v.y + v.z * v.z + v.w * v.w;
#pragma unroll
    for (int off = 32; off > 0; off >>= 1)
        s += __shfl_down(s, off, 64);
    if (lane == 0) wnorm[row] = s;
}

// ---------------------------------------------------------------------------
// Kernel 3: tiled fp32 GEMM-argmin, k-major LDS with vector (b128) reads.
// score(m,n) = wnorm[n] - 2 * dot(z[m], w[n])   (||z||^2 dropped: row-const)
// Zs[k][m]: thread reads m=rg*8..rg*8+7 as 2x float4 -> 4 distinct addrs/wave,
//           4 distinct bank-quads, broadcast over cg -> conflict-free.
// Ws[k][.]: deinterleaved so code n sits at pos = (n&4?64:0)+(n>>3)*4+(n&3);
//           16 cg-lanes' b128s then stride 16B -> 2 addrs/bank-quad (free).
__global__ __launch_bounds__(256, 4) void k_argmin(
        const float* __restrict__ zt, const float* __restrict__ w,
        const float* __restrict__ wnorm,
        float* __restrict__ pval, int* __restrict__ pidx) {
    __shared__ float Zs[TK][LDA];
    __shared__ float Ws[TK][LDA];
    const int tid = threadIdx.x;       // 0..255
    const int cg  = tid & 15;          // column group: 8 codes
    const int rg  = tid >> 4;          // row group:    8 tokens
    const int m0  = blockIdx.x * TM;
    const int n0  = blockIdx.y * NPER;

    float minv[8];
    int   mini[8];
#pragma unroll
    for (int i = 0; i < 8; ++i) { minv[i] = 3.0e38f; mini[i] = 0x7fffffff; }

    for (int nt = 0; nt < NPER; nt += TN) {
        float acc[8][8];
#pragma unroll
        for (int j = 0; j < 8; ++j) {
            const float wn = wnorm[n0 + nt + cg * 8 + j];
#pragma unroll
            for (int i = 0; i < 8; ++i) acc[i][j] = wn;
        }
        for (int k0 = 0; k0 < Kdim; k0 += TK) {
            __syncthreads();
#pragma unroll
            for (int p = 0; p < 4; ++p) {
                const int q = p * 256 + tid;
                const int r = q >> 3;      // row (m or n) within tile
                const int f = q & 7;       // float4 k-slot
                float4 v = *(const float4*)(zt + (size_t)(m0 + r) * Kdim + k0 + f * 4);
                Zs[f * 4 + 0][r] = -2.0f * v.x;
                Zs[f * 4 + 1][r] = -2.0f * v.y;
                Zs[f * 4 + 2][r] = -2.0f * v.z;
                Zs[f * 4 + 3][r] = -2.0f * v.w;
                float4 u = *(const float4*)(w + (size_t)(n0 + nt + r) * Kdim + k0 + f * 4);
                const int pos = ((r & 4) ? 64 : 0) + (r >> 3) * 4 + (r & 3);
                Ws[f * 4 + 0][pos] = u.x;
                Ws[f * 4 + 1][pos] = u.y;
                Ws[f * 4 + 2][pos] = u.z;
                Ws[f * 4 + 3][pos] = u.w;
            }
            __syncthreads();
#pragma unroll 4
            for (int k = 0; k < TK; ++k) {
                const float4 za0 = *(const float4*)&Zs[k][rg * 8];
                const float4 za1 = *(const float4*)&Zs[k][rg * 8 + 4];
                const float4 wb0 = *(const float4*)&Ws[k][cg * 4];        // codes cg*8+0..3
                const float4 wb1 = *(const float4*)&Ws[k][64 + cg * 4];   // codes cg*8+4..7
                const float za[8] = {za0.x, za0.y, za0.z, za0.w,
                                     za1.x, za1.y, za1.z, za1.w};
                const float wb[8] = {wb0.x, wb0.y, wb0.z, wb0.w,
                                     wb1.x, wb1.y, wb1.z, wb1.w};
#pragma unroll
                for (int i = 0; i < 8; ++i)
#pragma unroll
                    for (int j = 0; j < 8; ++j)
                        acc[i][j] = fmaf(za[i], wb[j], acc[i][j]);
            }
        }
#pragma unroll
        for (int i = 0; i < 8; ++i)
#pragma unroll
            for (int j = 0; j < 8; ++j) {
                const float v  = acc[i][j];
                const int  idx = n0 + nt + cg * 8 + j;
                if (v < minv[i] || (v == minv[i] && idx < mini[i])) {
                    minv[i] = v; mini[i] = idx;
                }
            }
    }

    // block reduction: 16 cg-threads per token row -> one (val,idx) per row
    __syncthreads();
    float* redv = (float*)&Zs[0][0];   // [TM][16] floats (8 KB, fits)
    int*   redi = (int*)&Ws[0][0];     // [TM][16] ints
#pragma unroll
    for (int i = 0; i < 8; ++i) {
        redv[(rg * 8 + i) * 16 + cg] = minv[i];
        redi[(rg * 8 + i) * 16 + cg] = mini[i];
    }
    __syncthreads();
    if (tid < TM) {
        float bv = 3.0e38f; int bi = 0x7fffffff;
#pragma unroll
        for (int c = 0; c < 16; ++c) {
            const float v = redv[tid * 16 + c];
            const int   x = redi[tid * 16 + c];
            if (v < bv || (v == bv && x < bi)) { bv = v; bi = x; }
        }
        pval[(size_t)blockIdx.y * Mtok + m0 + tid] = bv;
        pidx[(size_t)blockIdx.y * Mtok + m0 + tid] = bi;
    }
}

// ---------------------------------------------------------------------------
// Kernel 4: merge NSPLIT partials, gather z_q = weight[idx], write float idx.
// One wave per token.
__global__ __launch_bounds__(256) void k_gather(
        const float* __restrict__ w,
        const float* __restrict__ pval, const int* __restrict__ pidx,
        float* __restrict__ zq, float* __restrict__ idx_out) {
    const int token = blockIdx.x * 4 + (threadIdx.x >> 6);
    const int lane  = threadIdx.x & 63;
    float bv = 3.0e38f; int bi = 0x7fffffff;
#pragma unroll
    for (int s = 0; s < NSPLIT; ++s) {
        const float v = pval[(size_t)s * Mtok + token];
        const int   x = pidx[(size_t)s * Mtok + token];
        if (v < bv || (v == bv && x < bi)) { bv = v; bi = x; }
    }
    const float4 u = *(const float4*)(w + (size_t)bi * Kdim + lane * 4);
    *(float4*)(zq + (size_t)token * Kdim + lane * 4) = u;
    if (lane == 0) idx_out[token] = (float)bi;
}

// ---------------------------------------------------------------------------
extern "C" void kernel_launch(void* const* d_in, const int* in_sizes, int n_in,
                              void* d_out, int out_size, void* d_ws, size_t ws_size,
                              hipStream_t stream) {
    const float* z = (const float*)d_in[0];
    const float* w = (const float*)d_in[1];

    float* z_out  = (float*)d_out;                          // [16384, 256]
    float* zq     = z_out + (size_t)Mtok * Kdim;            // [16384, 256]
    float* idxout = zq + (size_t)Mtok * Kdim;               // [16384]

    float* wnorm  = (float*)d_ws;                           // [8192]
    float* pval   = wnorm + Ncode;                          // [NSPLIT*16384]
    int*   pidx   = (int*)(pval + (size_t)NSPLIT * Mtok);   // [NSPLIT*16384]

    k_transpose<<<dim3(HWdim / 32, Cdim / 32, Bdim), dim3(32, 8), 0, stream>>>(z, z_out);
    k_wnorm<<<dim3(Ncode), dim3(64), 0, stream>>>(w, wnorm);
    k_argmin<<<dim3(Mtok / TM, NSPLIT), dim3(256), 0, stream>>>(z_out, w, wnorm, pval, pidx);
    k_gather<<<dim3(Mtok / 4), dim3(256), 0, stream>>>(w, pval, pidx, zq, idxout);
}

// Round 3
// 882.518 us; speedup vs baseline: 1.3655x; 1.0342x over previous
//
#include <hip/hip_runtime.h>
#include <hip/hip_bf16.h>
#include <cstddef>
#include <cstdint>

typedef unsigned short u16;

#define Mtok  16384
#define Ncode 8192
#define Kdim  256
#define NSPLIT 8
#define NPER  (Ncode / NSPLIT)    // 1024 codes per split
#define NT    (NPER / 128)        // 8 column tiles of 128 per block
#define TH_MARGIN 0.02f

typedef __bf16 bf16x8 __attribute__((ext_vector_type(8)));
typedef float  f32x4  __attribute__((ext_vector_type(4)));

#define LDSP(p) ((__attribute__((address_space(3))) void*)(p))
#define GPTR(p) ((const __attribute__((address_space(1))) void*)(p))

__device__ __forceinline__ u16 f2bf(float x) {
    __hip_bfloat16 h = __float2bfloat16(x);
    return *reinterpret_cast<u16*>(&h);
}
__device__ __forceinline__ float bf2f(u16 u) {
    __hip_bfloat16 h = *reinterpret_cast<__hip_bfloat16*>(&u);
    return __bfloat162float(h);
}

// ---------------------------------------------------------------------------
// Kernel 1: transpose z -> z_out (fp32), plus bf16 split of s = -2*z:
// sh = bf16(s), sl = bf16(s - sh), stored [Mtok][256] row-major.
__global__ __launch_bounds__(256) void k_prep(const float* __restrict__ z,
        float* __restrict__ z_out, u16* __restrict__ sh, u16* __restrict__ sl) {
    __shared__ float tile[32][33];
    const int b  = blockIdx.z;
    const int c0 = blockIdx.y * 32;
    const int p0 = blockIdx.x * 32;
    const int tx = threadIdx.x;   // 0..31
    const int ty = threadIdx.y;   // 0..7
    const float* src = z + ((size_t)b * Kdim + c0) * 1024 + p0;
#pragma unroll
    for (int i = 0; i < 32; i += 8)
        tile[ty + i][tx] = src[(size_t)(ty + i) * 1024 + tx];
    __syncthreads();
#pragma unroll
    for (int i = 0; i < 32; i += 8) {
        const float v = tile[tx][ty + i];
        const size_t m = (size_t)b * 1024 + p0 + ty + i;
        const int    c = c0 + tx;
        z_out[m * Kdim + c] = v;
        const float s  = -2.0f * v;
        const u16   hb = f2bf(s);
        const u16   lb = f2bf(s - bf2f(hb));
        sh[m * Kdim + c] = hb;
        sl[m * Kdim + c] = lb;
    }
}

// ---------------------------------------------------------------------------
// Kernel 2: per-code ||w||^2 plus bf16 split wh/wl. One wave per code row.
__global__ __launch_bounds__(64) void k_wsplit(const float* __restrict__ w,
        float* __restrict__ wnorm, u16* __restrict__ wh, u16* __restrict__ wl) {
    const int row  = blockIdx.x;
    const int lane = threadIdx.x;
    const float4 v = ((const float4*)(w + (size_t)row * Kdim))[lane];
    float s = v.x * v.x + v.y * v.y + v.z * v.z + v.w * v.w;
#pragma unroll
    for (int off = 32; off > 0; off >>= 1)
        s += __shfl_down(s, off, 64);
    if (lane == 0) wnorm[row] = s;
    const float e[4] = {v.x, v.y, v.z, v.w};
    ushort4 ph, pl;
    u16* hp = (u16*)&ph; u16* lp = (u16*)&pl;
#pragma unroll
    for (int i = 0; i < 4; ++i) {
        const u16 hb = f2bf(e[i]);
        hp[i] = hb;
        lp[i] = f2bf(e[i] - bf2f(hb));
    }
    *(ushort4*)(wh + (size_t)row * Kdim + lane * 4) = ph;
    *(ushort4*)(wl + (size_t)row * Kdim + lane * 4) = pl;
}

// ---------------------------------------------------------------------------
// Kernel 3: bf16 MFMA distance GEMM + per-row running top-2 (val1, idx1, val2).
// d(m,n) = wnorm[n] + sum over 3 passes (sh*wh + sh*wl + sl*wh).
// Block: 256 thr = 4 waves; 128x128 tile; wave w owns rows w*32..w*32+31,
// all 128 cols, as 2x8 frags of 16x16x32. Grid: 1024 blocks, bid&7 = n-split
// (XCD-pinned for B L2 residency), bid>>3 = m-tile.
__global__ __launch_bounds__(256) void k_mfma(
        const u16* __restrict__ sh, const u16* __restrict__ sl,
        const u16* __restrict__ wh, const u16* __restrict__ wl,
        const float* __restrict__ wnorm,
        float* __restrict__ pv1, int* __restrict__ pi1, float* __restrict__ pv2) {
    __shared__ __align__(16) u16 As[128 * 32];
    __shared__ __align__(16) u16 Bs[128 * 32];
    const int tid  = threadIdx.x;
    const int w    = tid >> 6;          // wave 0..3
    const int lane = tid & 63;
    const int l15  = lane & 15;
    const int q    = lane >> 4;         // 0..3
    const int y    = blockIdx.x & 7;    // n-split (XCD pin)
    const int x    = blockIdx.x >> 3;   // m-tile
    const int m0   = x * 128;
    const int n0   = y * NPER;
    // staging decomposition: 64 lanes = 16 rows x 4 16B-chunks
    const int srow = lane >> 2;         // 0..15
    const int sq   = lane & 3;          // k-chunk: 8 bf16 = 16 B

    const u16* Alist[3] = {sh, sh, sl};
    const u16* Blist[3] = {wh, wl, wh};

    float v1[8], v2[8]; int i1[8];      // slot s = i*4+reg -> row m0+w*32+i*16+q*4+reg
#pragma unroll
    for (int s = 0; s < 8; ++s) { v1[s] = 3.0e38f; v2[s] = 3.0e38f; i1[s] = 0x7fffffff; }

    for (int nt = 0; nt < NT; ++nt) {
        const int nb = n0 + nt * 128;
        f32x4 acc[2][8];
#pragma unroll
        for (int j = 0; j < 8; ++j) {
            const float wv = wnorm[nb + j * 16 + l15];
#pragma unroll
            for (int i = 0; i < 2; ++i) {
                acc[i][j][0] = wv; acc[i][j][1] = wv;
                acc[i][j][2] = wv; acc[i][j][3] = wv;
            }
        }
#pragma unroll 1
        for (int pr = 0; pr < 3; ++pr) {
            const u16* Ag = Alist[pr];
            const u16* Bg = Blist[pr];
#pragma unroll 1
            for (int k0 = 0; k0 < Kdim; k0 += 32) {
                __syncthreads();
#pragma unroll
                for (int t = 0; t < 2; ++t) {
                    const int r = w * 32 + t * 16 + srow;
                    __builtin_amdgcn_global_load_lds(
                        GPTR(Ag + (size_t)(m0 + r) * Kdim + k0 + sq * 8),
                        LDSP(As + (w * 32 + t * 16) * 32), 16, 0, 0);
                    __builtin_amdgcn_global_load_lds(
                        GPTR(Bg + (size_t)(nb + r) * Kdim + k0 + sq * 8),
                        LDSP(Bs + (w * 32 + t * 16) * 32), 16, 0, 0);
                }
                __syncthreads();
                bf16x8 a[2], bfr[8];
#pragma unroll
                for (int i = 0; i < 2; ++i)
                    a[i] = *(const bf16x8*)&As[(w * 32 + i * 16 + l15) * 32 + q * 8];
#pragma unroll
                for (int j = 0; j < 8; ++j)
                    bfr[j] = *(const bf16x8*)&Bs[(j * 16 + l15) * 32 + q * 8];
#pragma unroll
                for (int i = 0; i < 2; ++i)
#pragma unroll
                    for (int j = 0; j < 8; ++j)
                        acc[i][j] = __builtin_amdgcn_mfma_f32_16x16x32_bf16(
                            a[i], bfr[j], acc[i][j], 0, 0, 0);
            }
        }
        // top-2 update (idx ascending within a lane's scan -> strict < = first-min)
#pragma unroll
        for (int i = 0; i < 2; ++i)
#pragma unroll
            for (int r = 0; r < 4; ++r) {
                const int s = i * 4 + r;
#pragma unroll
                for (int j = 0; j < 8; ++j) {
                    const float d   = acc[i][j][r];
                    const int   idx = nb + j * 16 + l15;
                    const bool  bt  = d < v1[s];
                    const float lose = bt ? v1[s] : d;
                    v2[s] = fminf(v2[s], lose);
                    v1[s] = bt ? d : v1[s];
                    i1[s] = bt ? idx : i1[s];
                }
            }
    }
    // butterfly merge across the 16 lanes sharing each row (lex on idx)
#pragma unroll
    for (int msk = 1; msk < 16; msk <<= 1) {
#pragma unroll
        for (int s = 0; s < 8; ++s) {
            const float ov1 = __shfl_xor(v1[s], msk, 64);
            const int   oi1 = __shfl_xor(i1[s], msk, 64);
            const float ov2 = __shfl_xor(v2[s], msk, 64);
            const bool  keep = (v1[s] < ov1) || (v1[s] == ov1 && i1[s] < oi1);
            const float lose = keep ? ov1 : v1[s];
            v1[s] = keep ? v1[s] : ov1;
            i1[s] = keep ? i1[s] : oi1;
            v2[s] = fminf(fminf(v2[s], ov2), lose);
        }
    }
    if (l15 == 0) {
#pragma unroll
        for (int i = 0; i < 2; ++i)
#pragma unroll
            for (int r = 0; r < 4; ++r) {
                const int s = i * 4 + r;
                const int m = m0 + w * 32 + i * 16 + q * 4 + r;
                pv1[(size_t)y * Mtok + m] = v1[s];
                pi1[(size_t)y * Mtok + m] = i1[s];
                pv2[(size_t)y * Mtok + m] = v2[s];
            }
    }
}

// ---------------------------------------------------------------------------
// Kernel 4: merge 8 split partials -> provisional idx + ambiguity flag.
__global__ __launch_bounds__(256) void k_merge(
        const float* __restrict__ pv1, const int* __restrict__ pi1,
        const float* __restrict__ pv2, int* __restrict__ fidx,
        int* __restrict__ flag) {
    const int t = blockIdx.x * 256 + threadIdx.x;
    float b1 = 3.0e38f, b2 = 3.0e38f; int bi = 0x7fffffff;
#pragma unroll
    for (int s = 0; s < NSPLIT; ++s) {
        const float v1 = pv1[(size_t)s * Mtok + t];
        const int   i1 = pi1[(size_t)s * Mtok + t];
        const float v2 = pv2[(size_t)s * Mtok + t];
        const bool  wn = (v1 < b1) || (v1 == b1 && i1 < bi);
        const float lose = wn ? b1 : v1;
        b2 = fminf(fminf(b2, v2), lose);
        b1 = wn ? v1 : b1;
        bi = wn ? i1 : bi;
    }
    fidx[t] = bi;
    flag[t] = (b2 - b1 < TH_MARGIN) ? 1 : 0;
}

// ---------------------------------------------------------------------------
// Kernel 5: exact fp32 rescore for flagged tokens (one block per token).
__global__ __launch_bounds__(256) void k_rescue(
        const float* __restrict__ z_out, const float* __restrict__ w,
        const float* __restrict__ wnorm, const int* __restrict__ flag,
        int* __restrict__ fidx) {
    const int t = blockIdx.x;
    if (!flag[t]) return;
    __shared__ float zr[256];
    __shared__ float rv[256];
    __shared__ int   ri[256];
    const int tid = threadIdx.x;
    zr[tid] = z_out[(size_t)t * Kdim + tid];
    __syncthreads();
    float bd = 3.0e38f; int bn = 0x7fffffff;
    for (int n = tid; n < Ncode; n += 256) {   // n ascending per thread
        const float4* wr = (const float4*)(w + (size_t)n * Kdim);
        float s0 = 0.f, s1 = 0.f, s2 = 0.f, s3 = 0.f;
#pragma unroll 8
        for (int kk = 0; kk < 64; ++kk) {
            const float4 wv = wr[kk];
            const float4 zv = *(const float4*)&zr[kk * 4];
            s0 = fmaf(zv.x, wv.x, s0);
            s1 = fmaf(zv.y, wv.y, s1);
            s2 = fmaf(zv.z, wv.z, s2);
            s3 = fmaf(zv.w, wv.w, s3);
        }
        const float d = wnorm[n] - 2.0f * ((s0 + s1) + (s2 + s3));
        if (d < bd) { bd = d; bn = n; }
    }
    rv[tid] = bd; ri[tid] = bn;
    __syncthreads();
    for (int st = 128; st > 0; st >>= 1) {
        if (tid < st) {
            const float ov = rv[tid + st]; const int oi = ri[tid + st];
            if (ov < rv[tid] || (ov == rv[tid] && oi < ri[tid])) {
                rv[tid] = ov; ri[tid] = oi;
            }
        }
        __syncthreads();
    }
    if (tid == 0) fidx[t] = ri[0];
}

// ---------------------------------------------------------------------------
// Kernel 6: gather z_q = weight[fidx], write float indices. One wave/token.
__global__ __launch_bounds__(256) void k_gather(
        const float* __restrict__ w, const int* __restrict__ fidx,
        float* __restrict__ zq, float* __restrict__ idx_out) {
    const int token = blockIdx.x * 4 + (threadIdx.x >> 6);
    const int lane  = threadIdx.x & 63;
    const int bi    = fidx[token];
    const float4 u = *(const float4*)(w + (size_t)bi * Kdim + lane * 4);
    *(float4*)(zq + (size_t)token * Kdim + lane * 4) = u;
    if (lane == 0) idx_out[token] = (float)bi;
}

// ---------------------------------------------------------------------------
extern "C" void kernel_launch(void* const* d_in, const int* in_sizes, int n_in,
                              void* d_out, int out_size, void* d_ws, size_t ws_size,
                              hipStream_t stream) {
    const float* z = (const float*)d_in[0];
    const float* w = (const float*)d_in[1];

    float* z_out  = (float*)d_out;                          // [16384, 256]
    float* zq     = z_out + (size_t)Mtok * Kdim;            // [16384, 256]
    float* idxout = zq + (size_t)Mtok * Kdim;               // [16384]

    char* ws = (char*)d_ws;
    u16*   sh    = (u16*)ws;                       ws += (size_t)Mtok * Kdim * 2;
    u16*   sl    = (u16*)ws;                       ws += (size_t)Mtok * Kdim * 2;
    u16*   wh    = (u16*)ws;                       ws += (size_t)Ncode * Kdim * 2;
    u16*   wl    = (u16*)ws;                       ws += (size_t)Ncode * Kdim * 2;
    float* wnorm = (float*)ws;                     ws += (size_t)Ncode * 4;
    float* pv1   = (float*)ws;                     ws += (size_t)NSPLIT * Mtok * 4;
    int*   pi1   = (int*)ws;                       ws += (size_t)NSPLIT * Mtok * 4;
    float* pv2   = (float*)ws;                     ws += (size_t)NSPLIT * Mtok * 4;
    int*   fidx  = (int*)ws;                       ws += (size_t)Mtok * 4;
    int*   flag  = (int*)ws;                       ws += (size_t)Mtok * 4;

    k_prep<<<dim3(1024 / 32, Kdim / 32, 16), dim3(32, 8), 0, stream>>>(z, z_out, sh, sl);
    k_wsplit<<<dim3(Ncode), dim3(64), 0, stream>>>(w, wnorm, wh, wl);
    k_mfma<<<dim3(128 * NSPLIT), dim3(256), 0, stream>>>(sh, sl, wh, wl, wnorm,
                                                         pv1, pi1, pv2);
    k_merge<<<dim3(Mtok / 256), dim3(256), 0, stream>>>(pv1, pi1, pv2, fidx, flag);
    k_rescue<<<dim3(Mtok), dim3(256), 0, stream>>>(z_out, w, wnorm, flag, fidx);
    k_gather<<<dim3(Mtok / 4), dim3(256), 0, stream>>>(w, fidx, zq, idxout);
}